// Round 4
// baseline (195.076 us; speedup 1.0000x reference)
//
#include <hip/hip_runtime.h>
#include <math.h>

#define DD 256

typedef float  f32x4  __attribute__((ext_vector_type(4)));
typedef short  bf16x8 __attribute__((ext_vector_type(8)));

__device__ __forceinline__ unsigned short f2bf(float f) {
    unsigned int u = __float_as_uint(f);
    u = (u + 0x7fffu + ((u >> 16) & 1u)) >> 16;  // RNE
    return (unsigned short)u;
}
__device__ __forceinline__ float bf2f(unsigned int h16) {
    return __uint_as_float(h16 << 16);
}

// ---------------------------------------------------------------------------
// Universal-layer p-vector. Uniform state is preserved exactly by the
// circulant update (roll-difference == 0), so s0 = 0.0625 * prod cos(ang).
// ---------------------------------------------------------------------------
__global__ __launch_bounds__(256)
void universal_p_kernel(const float* __restrict__ u1_w,
                        const float* __restrict__ u2_w,
                        float* __restrict__ p_out /* [512]: p1 then p2 */) {
    const int j = threadIdx.x;
    const float* uw = blockIdx.x ? u2_w : u1_w;
    float s = 0.0625f;  // 1/sqrt(256)
#pragma unroll
    for (int d = 0; d < 9; ++d)
#pragma unroll
        for (int g = 0; g < 3; ++g)
            s *= cosf(uw[d * DD * DD + j * DD + g]);
    p_out[blockIdx.x * DD + j] = s * s;
}

// ---------------------------------------------------------------------------
// Weight prep: fp32 -> bf16, [n][k] (B^T) layout; cw transposed.
// ---------------------------------------------------------------------------
__global__ __launch_bounds__(256)
void prep_weights(const float* __restrict__ w0, const float* __restrict__ w1,
                  const float* __restrict__ cw1, const float* __restrict__ w2,
                  const float* __restrict__ cw2, const float* __restrict__ wo,
                  unsigned short* __restrict__ wall) {
    const int mat = blockIdx.y;
    const int n = blockIdx.x;
    const int k = threadIdx.x;
    const float* src;
    bool tr = false;
    switch (mat) {
        case 0: src = w0; break;
        case 1: src = w1; break;
        case 2: src = cw1; tr = true; break;
        case 3: src = w2; break;
        case 4: src = cw2; tr = true; break;
        default: src = wo; break;
    }
    const float v = tr ? src[k * DD + n] : src[n * DD + k];
    wall[mat * 65536 + n * DD + k] = f2bf(v);
}

// ---------------------------------------------------------------------------
// LDS activation layout: 16B chunks, chunk (m, kc) at kc*64 + (m ^ (kc&7)).
// ---------------------------------------------------------------------------
__device__ __forceinline__ int chunk_idx(int m, int kc) {
    return kc * 64 + (m ^ (kc & 7));
}

__device__ __forceinline__ float fast_tanh(float x) {
    const float e = __expf(2.0f * x);
    return 1.0f - 2.0f * __builtin_amdgcn_rcpf(1.0f + e);
}

__device__ __forceinline__ void prefetch_W(bf16x8 (&slot)[4],
                                           const unsigned short* __restrict__ W,
                                           int k0, int nb, int l15, int quad) {
    const int koff = k0 * 32 + quad * 8;
#pragma unroll
    for (int nt = 0; nt < 4; ++nt)
        slot[nt] = *(const bf16x8*)&W[(nb + nt * 16 + l15) * DD + koff];
}

// ---------------------------------------------------------------------------
// One fused layer, in-place activations. A <- W rows (n), B <- h rows (m);
// D: row(quad*4+r) -> n, col(lane&15) -> m. W ring depth 3, slot of step
// (L,k0) = (2L+k0)%3; PHASE = (2L)%3. On entry slots PHASE, PHASE+1 hold
// k0=0,1 (primed by the previous layer's steps 6,7). Steps 6,7 prime Wn.
// ---------------------------------------------------------------------------
template <int PHASE, int MODE>  // MODE 0: relu, 1: tanh(+p)
__device__ __forceinline__ void layer_step(uint4* h, bf16x8 (&wr)[3][4],
                                           const unsigned short* __restrict__ W,
                                           const unsigned short* __restrict__ Wn,
                                           const float* __restrict__ bias,
                                           const float* __restrict__ pv) {
    const int tid  = threadIdx.x;
    const int wave = tid >> 6;
    const int lane = tid & 63;
    const int quad = lane >> 4;
    const int l15  = lane & 15;
    const int nb   = wave * 64;

    f32x4 acc[4][4];  // [nt][mt]
#pragma unroll
    for (int nt = 0; nt < 4; ++nt)
#pragma unroll
        for (int mt = 0; mt < 4; ++mt) acc[nt][mt] = (f32x4){0.f, 0.f, 0.f, 0.f};

    bf16x8 h_f[2][4];
#pragma unroll
    for (int mt = 0; mt < 4; ++mt)  // k0 = 0 fragments (kc = quad)
        h_f[0][mt] = *(const bf16x8*)&h[chunk_idx(mt * 16 + l15, quad)];

#pragma unroll
    for (int k0 = 0; k0 < 8; ++k0) {
        const int cur = (PHASE + k0) % 3;
        const int pf  = (PHASE + k0 + 2) % 3;
        if (k0 < 6) prefetch_W(wr[pf], W, k0 + 2, nb, l15, quad);
        else        prefetch_W(wr[pf], Wn, k0 - 6, nb, l15, quad);
        if (k0 < 7) {
            const int kc = (k0 + 1) * 4 + quad;
#pragma unroll
            for (int mt = 0; mt < 4; ++mt)
                h_f[(k0 + 1) & 1][mt] =
                    *(const bf16x8*)&h[chunk_idx(mt * 16 + l15, kc)];
        }
#pragma unroll
        for (int nt = 0; nt < 4; ++nt)
#pragma unroll
            for (int mt = 0; mt < 4; ++mt)
                acc[nt][mt] = __builtin_amdgcn_mfma_f32_16x16x32_bf16(
                    wr[cur][nt], h_f[k0 & 1][mt], acc[nt][mt], 0, 0, 0);
    }

    __syncthreads();  // everyone done READING h -> safe to overwrite in place

    // epilogue: thread holds n = n0..n0+3 (consecutive), m = mt*16 + l15
#pragma unroll
    for (int nt = 0; nt < 4; ++nt) {
        const int n0 = nb + nt * 16 + quad * 4;
        f32x4 add = *(const f32x4*)&bias[n0];
        if (MODE == 1) add += *(const f32x4*)&pv[n0];
        const int kc_o = n0 >> 3;
        const int half = quad & 1;
#pragma unroll
        for (int mt = 0; mt < 4; ++mt) {
            const f32x4 v = acc[nt][mt] + add;
            float t0, t1, t2, t3;
            if (MODE == 1) {
                t0 = fast_tanh(v.x); t1 = fast_tanh(v.y);
                t2 = fast_tanh(v.z); t3 = fast_tanh(v.w);
            } else {
                t0 = fmaxf(v.x, 0.f); t1 = fmaxf(v.y, 0.f);
                t2 = fmaxf(v.z, 0.f); t3 = fmaxf(v.w, 0.f);
            }
            uint2 u;
            u.x = (unsigned int)f2bf(t0) | ((unsigned int)f2bf(t1) << 16);
            u.y = (unsigned int)f2bf(t2) | ((unsigned int)f2bf(t3) << 16);
            *(uint2*)((char*)&h[chunk_idx(mt * 16 + l15, kc_o)] + half * 8) = u;
        }
    }
    __syncthreads();  // writes visible for next layer
}

__global__ __launch_bounds__(256, 3)
void unet_fused(const float* __restrict__ x,
                const unsigned short* __restrict__ wall,
                const float* __restrict__ b0, const float* __restrict__ b1,
                const float* __restrict__ cb1, const float* __restrict__ b2,
                const float* __restrict__ cb2, const float* __restrict__ bo,
                const float* __restrict__ pbuf,
                float* __restrict__ out) {
    __shared__ uint4 h[2048];  // 32 KB, chunked+swizzled bf16, in-place
    const int m0 = blockIdx.x * 64;
    const int tid = threadIdx.x;
    const int wave = tid >> 6;
    const int lane = tid & 63;
    const int quad = lane >> 4;
    const int l15  = lane & 15;
    const int nb   = wave * 64;

    // prime layer-0 W ring (slots 0,1) BEFORE x staging so latency overlaps
    bf16x8 wr[3][4];
    prefetch_W(wr[0], wall, 0, nb, l15, quad);
    prefetch_W(wr[1], wall, 1, nb, l15, quad);

    // stage x (fp32, coalesced) -> h (bf16 chunks)
    const int c4 = tid & 63;            // float4 column index (k = c4*4)
    const int rbase = (tid >> 6) * 16;
    const int kc_s = c4 >> 1;
    const int half_s = c4 & 1;
#pragma unroll
    for (int i = 0; i < 16; ++i) {
        const int row = rbase + i;
        const float4 v = *(const float4*)&x[(size_t)(m0 + row) * DD + c4 * 4];
        uint2 u;
        u.x = (unsigned int)f2bf(v.x) | ((unsigned int)f2bf(v.y) << 16);
        u.y = (unsigned int)f2bf(v.z) | ((unsigned int)f2bf(v.w) << 16);
        *(uint2*)((char*)&h[chunk_idx(row, kc_s)] + half_s * 8) = u;
    }
    __syncthreads();

    // phases: (2L) % 3 = 0,2,1,0,2,1
    layer_step<0, 0>(h, wr, wall + 0 * 65536, wall + 1 * 65536, b0, nullptr);
    layer_step<2, 0>(h, wr, wall + 1 * 65536, wall + 2 * 65536, b1, nullptr);
    layer_step<1, 1>(h, wr, wall + 2 * 65536, wall + 3 * 65536, cb1, pbuf);
    layer_step<0, 0>(h, wr, wall + 3 * 65536, wall + 4 * 65536, b2, nullptr);
    layer_step<2, 1>(h, wr, wall + 4 * 65536, wall + 5 * 65536, cb2, pbuf + 256);
    layer_step<1, 0>(h, wr, wall + 5 * 65536, wall + 0 * 65536, bo, nullptr);

    // final activations (bf16) -> fp32, coalesced float4 stores
#pragma unroll
    for (int i = 0; i < 16; ++i) {
        const int row = rbase + i;
        const uint2 u = *(const uint2*)((char*)&h[chunk_idx(row, kc_s)] + half_s * 8);
        float4 v;
        v.x = bf2f(u.x & 0xffffu); v.y = bf2f(u.x >> 16);
        v.z = bf2f(u.y & 0xffffu); v.w = bf2f(u.y >> 16);
        *(float4*)&out[(size_t)(m0 + row) * DD + c4 * 4] = v;
    }
}

// ---------------------------------------------------------------------------
extern "C" void kernel_launch(void* const* d_in, const int* in_sizes, int n_in,
                              void* d_out, int out_size, void* d_ws, size_t ws_size,
                              hipStream_t stream) {
    const float* x      = (const float*)d_in[0];
    const float* lin0_w = (const float*)d_in[1];
    const float* lin0_b = (const float*)d_in[2];
    const float* lin1_w = (const float*)d_in[3];
    const float* lin1_b = (const float*)d_in[4];
    const float* u1_w   = (const float*)d_in[5];
    const float* u1_cw  = (const float*)d_in[6];
    const float* u1_cb  = (const float*)d_in[7];
    const float* lin2_w = (const float*)d_in[8];
    const float* lin2_b = (const float*)d_in[9];
    const float* u2_w   = (const float*)d_in[10];
    const float* u2_cw  = (const float*)d_in[11];
    const float* u2_cb  = (const float*)d_in[12];
    const float* lino_w = (const float*)d_in[13];
    const float* lino_b = (const float*)d_in[14];

    float* out = (float*)d_out;
    unsigned short* wall = (unsigned short*)d_ws;         // 6*65536 bf16 = 768 KB
    float* pbuf = (float*)((char*)d_ws + 6 * 65536 * 2);  // 512 floats

    universal_p_kernel<<<dim3(2), dim3(256), 0, stream>>>(u1_w, u2_w, pbuf);
    prep_weights<<<dim3(256, 6), dim3(256), 0, stream>>>(
        lin0_w, lin1_w, u1_cw, lin2_w, u2_cw, lino_w, wall);
    unet_fused<<<dim3(512), dim3(256), 0, stream>>>(
        x, wall, lin0_b, lin1_b, u1_cb, lin2_b, u2_cb, lino_b, pbuf, out);
}

// Round 5
// 153.094 us; speedup vs baseline: 1.2742x; 1.2742x over previous
//
#include <hip/hip_runtime.h>
#include <math.h>

#define DD 256

typedef float  f32x4  __attribute__((ext_vector_type(4)));
typedef short  bf16x8 __attribute__((ext_vector_type(8)));

__device__ __forceinline__ unsigned short f2bf(float f) {
    unsigned int u = __float_as_uint(f);
    u = (u + 0x7fffu + ((u >> 16) & 1u)) >> 16;  // RNE
    return (unsigned short)u;
}
__device__ __forceinline__ float bf2f(unsigned int h16) {
    return __uint_as_float(h16 << 16);
}

// ---------------------------------------------------------------------------
// Universal-layer p-vector. Uniform state is preserved exactly by the
// circulant update (roll-difference == 0), so s0 = 0.0625 * prod cos(ang).
// Verified vs full simulation in R1/R2 (identical absmax).
// ---------------------------------------------------------------------------
__global__ __launch_bounds__(256)
void universal_p_kernel(const float* __restrict__ u1_w,
                        const float* __restrict__ u2_w,
                        float* __restrict__ p_out /* [512]: p1 then p2 */) {
    const int j = threadIdx.x;
    const float* uw = blockIdx.x ? u2_w : u1_w;
    float s = 0.0625f;  // 1/sqrt(256)
#pragma unroll
    for (int d = 0; d < 9; ++d)
#pragma unroll
        for (int g = 0; g < 3; ++g)
            s *= cosf(uw[d * DD * DD + j * DD + g]);
    p_out[blockIdx.x * DD + j] = s * s;
}

// ---------------------------------------------------------------------------
// Weight prep: fp32 -> bf16 in MFMA-FRAGMENT-LINEAR order:
//   wall[mat][wb][k0][nt][lane] : 8 bf16 (16 B) per entry
//   holding W_bt[n = wb*64 + nt*16 + (lane&15)][k = k0*32 + (lane>>4)*8 .. +8]
// so a wave's fragment load is global_load_dwordx4 at base + lane*16,
// fully coalesced (1 KB/instr). cw matrices transposed here.
// One thread per 16 B chunk: 6*8192 = 49152 threads (192 blocks).
// ---------------------------------------------------------------------------
__global__ __launch_bounds__(256)
void prep_weights(const float* __restrict__ w0, const float* __restrict__ w1,
                  const float* __restrict__ cw1, const float* __restrict__ w2,
                  const float* __restrict__ cw2, const float* __restrict__ wo,
                  unsigned short* __restrict__ wall) {
    const int gid  = blockIdx.x * 256 + threadIdx.x;
    const int mat  = gid >> 13;
    const int rem  = gid & 8191;
    const int wb   = rem >> 11;
    const int rem2 = rem & 2047;
    const int k0   = rem2 >> 8;
    const int rem3 = rem2 & 255;
    const int nt   = rem3 >> 6;
    const int lane = rem3 & 63;
    const int n  = wb * 64 + nt * 16 + (lane & 15);
    const int kb = k0 * 32 + (lane >> 4) * 8;

    const float* src;
    bool tr = false;
    switch (mat) {
        case 0: src = w0; break;
        case 1: src = w1; break;
        case 2: src = cw1; tr = true; break;
        case 3: src = w2; break;
        case 4: src = cw2; tr = true; break;
        default: src = wo; break;
    }
    unsigned short tmp[8];
#pragma unroll
    for (int j = 0; j < 8; ++j) {
        const float v = tr ? src[(kb + j) * DD + n] : src[n * DD + kb + j];
        tmp[j] = f2bf(v);
    }
    *(uint4*)&wall[mat * 65536 + wb * 16384 + k0 * 2048 + nt * 512 + lane * 8] =
        *(const uint4*)tmp;
}

// ---------------------------------------------------------------------------
// LDS activation layout (32 rows): 16 B chunk (m, kc) at kc*32 + (m ^ (kc&7)).
// MFMA frag reads and epilogue writes are bank-conflict-free (verified R3).
// ---------------------------------------------------------------------------
__device__ __forceinline__ int chunk_idx(int m, int kc) {
    return kc * 32 + (m ^ (kc & 7));
}

__device__ __forceinline__ float fast_tanh(float x) {
    const float e = __expf(2.0f * x);
    return 1.0f - 2.0f * __builtin_amdgcn_rcpf(1.0f + e);
}

// ---------------------------------------------------------------------------
// One fused layer, in-place activations, 32 rows. A <- W rows (n), B <- h
// rows (m); D: row(quad*4+r) -> n, col(lane&15) -> m. Wave owns 64 n-units.
// W ring depth 2, slot = k0 & 1 (8 steps/layer => parity identical across
// layers; step 7 prefetches next layer's k0=0, completing under the
// epilogue + barrier).
// ---------------------------------------------------------------------------
template <int MODE>  // 0: relu, 1: tanh(+p)
__device__ __forceinline__ void layer_step(uint4* h, bf16x8 (&wr)[2][4],
                                           const unsigned short* __restrict__ W,
                                           const unsigned short* __restrict__ Wn,
                                           const float* __restrict__ bias,
                                           const float* __restrict__ pv) {
    const int tid  = threadIdx.x;
    const int wave = tid >> 6;
    const int lane = tid & 63;
    const int quad = lane >> 4;
    const int l15  = lane & 15;
    const unsigned short* Wb  = W  + wave * 16384 + lane * 8;
    const unsigned short* Wnb = Wn + wave * 16384 + lane * 8;

    f32x4 acc[4][2];  // [nt][mt]
#pragma unroll
    for (int nt = 0; nt < 4; ++nt)
#pragma unroll
        for (int mt = 0; mt < 2; ++mt) acc[nt][mt] = (f32x4){0.f, 0.f, 0.f, 0.f};

    bf16x8 h_f[2][2];
#pragma unroll
    for (int mt = 0; mt < 2; ++mt)  // k0 = 0 fragments (kc = quad)
        h_f[0][mt] = *(const bf16x8*)&h[chunk_idx(mt * 16 + l15, quad)];

#pragma unroll
    for (int k0 = 0; k0 < 8; ++k0) {
        const int cur = k0 & 1, nxt = cur ^ 1;
        {  // prefetch next k-step's W frags (next layer's k0=0 at step 7)
            const unsigned short* ws = (k0 < 7) ? &Wb[(k0 + 1) * 2048] : Wnb;
#pragma unroll
            for (int nt = 0; nt < 4; ++nt)
                wr[nxt][nt] = *(const bf16x8*)&ws[nt * 512];
        }
        if (k0 < 7) {
            const int kc = (k0 + 1) * 4 + quad;
#pragma unroll
            for (int mt = 0; mt < 2; ++mt)
                h_f[nxt][mt] = *(const bf16x8*)&h[chunk_idx(mt * 16 + l15, kc)];
        }
#pragma unroll
        for (int nt = 0; nt < 4; ++nt)
#pragma unroll
            for (int mt = 0; mt < 2; ++mt)
                acc[nt][mt] = __builtin_amdgcn_mfma_f32_16x16x32_bf16(
                    wr[cur][nt], h_f[cur][mt], acc[nt][mt], 0, 0, 0);
    }

    __syncthreads();  // all reads of h done -> safe to overwrite in place

    const int nb = wave * 64;
#pragma unroll
    for (int nt = 0; nt < 4; ++nt) {
        const int n0 = nb + nt * 16 + quad * 4;
        f32x4 add = *(const f32x4*)&bias[n0];
        if (MODE == 1) add += *(const f32x4*)&pv[n0];
        const int kc_o = n0 >> 3;
        const int half = quad & 1;
#pragma unroll
        for (int mt = 0; mt < 2; ++mt) {
            const f32x4 v = acc[nt][mt] + add;
            float t0, t1, t2, t3;
            if (MODE == 1) {
                t0 = fast_tanh(v.x); t1 = fast_tanh(v.y);
                t2 = fast_tanh(v.z); t3 = fast_tanh(v.w);
            } else {
                t0 = fmaxf(v.x, 0.f); t1 = fmaxf(v.y, 0.f);
                t2 = fmaxf(v.z, 0.f); t3 = fmaxf(v.w, 0.f);
            }
            uint2 u;
            u.x = (unsigned int)f2bf(t0) | ((unsigned int)f2bf(t1) << 16);
            u.y = (unsigned int)f2bf(t2) | ((unsigned int)f2bf(t3) << 16);
            *(uint2*)((char*)&h[chunk_idx(mt * 16 + l15, kc_o)] + half * 8) = u;
        }
    }
    __syncthreads();  // writes visible for next layer
}

__global__ __launch_bounds__(256, 2)
void unet_fused(const float* __restrict__ x,
                const unsigned short* __restrict__ wall,
                const float* __restrict__ b0, const float* __restrict__ b1,
                const float* __restrict__ cb1, const float* __restrict__ b2,
                const float* __restrict__ cb2, const float* __restrict__ bo,
                const float* __restrict__ pbuf,
                float* __restrict__ out) {
    __shared__ uint4 h[1024];  // 16 KB: 32 rows x 256 bf16, chunked+swizzled
    const int m0 = blockIdx.x * 32;
    const int tid = threadIdx.x;
    const int wave = tid >> 6;
    const int lane = tid & 63;

    // prime W ring slot 0 with layer-0 k0=0 BEFORE x staging (latency overlap)
    bf16x8 wr[2][4];
    {
        const unsigned short* ws = wall + wave * 16384 + lane * 8;
#pragma unroll
        for (int nt = 0; nt < 4; ++nt)
            wr[0][nt] = *(const bf16x8*)&ws[nt * 512];
    }

    // stage x (fp32, coalesced reads) -> h (bf16 chunks)
    const int c4 = tid & 63;            // float4 column index (k = c4*4)
    const int rbase = (tid >> 6) * 8;
    const int kc_s = c4 >> 1;
    const int half_s = c4 & 1;
#pragma unroll
    for (int i = 0; i < 8; ++i) {
        const int row = rbase + i;
        const float4 v = *(const float4*)&x[(size_t)(m0 + row) * DD + c4 * 4];
        uint2 u;
        u.x = (unsigned int)f2bf(v.x) | ((unsigned int)f2bf(v.y) << 16);
        u.y = (unsigned int)f2bf(v.z) | ((unsigned int)f2bf(v.w) << 16);
        *(uint2*)((char*)&h[chunk_idx(row, kc_s)] + half_s * 8) = u;
    }
    __syncthreads();

    layer_step<0>(h, wr, wall + 0 * 65536, wall + 1 * 65536, b0, nullptr);
    layer_step<0>(h, wr, wall + 1 * 65536, wall + 2 * 65536, b1, nullptr);
    layer_step<1>(h, wr, wall + 2 * 65536, wall + 3 * 65536, cb1, pbuf);
    layer_step<0>(h, wr, wall + 3 * 65536, wall + 4 * 65536, b2, nullptr);
    layer_step<1>(h, wr, wall + 4 * 65536, wall + 5 * 65536, cb2, pbuf + 256);
    layer_step<0>(h, wr, wall + 5 * 65536, wall + 0 * 65536, bo, nullptr);

    // final activations (bf16) -> fp32, coalesced float4 stores
#pragma unroll
    for (int i = 0; i < 8; ++i) {
        const int row = rbase + i;
        const uint2 u = *(const uint2*)((char*)&h[chunk_idx(row, kc_s)] + half_s * 8);
        float4 v;
        v.x = bf2f(u.x & 0xffffu); v.y = bf2f(u.x >> 16);
        v.z = bf2f(u.y & 0xffffu); v.w = bf2f(u.y >> 16);
        *(float4*)&out[(size_t)(m0 + row) * DD + c4 * 4] = v;
    }
}

// ---------------------------------------------------------------------------
extern "C" void kernel_launch(void* const* d_in, const int* in_sizes, int n_in,
                              void* d_out, int out_size, void* d_ws, size_t ws_size,
                              hipStream_t stream) {
    const float* x      = (const float*)d_in[0];
    const float* lin0_w = (const float*)d_in[1];
    const float* lin0_b = (const float*)d_in[2];
    const float* lin1_w = (const float*)d_in[3];
    const float* lin1_b = (const float*)d_in[4];
    const float* u1_w   = (const float*)d_in[5];
    const float* u1_cw  = (const float*)d_in[6];
    const float* u1_cb  = (const float*)d_in[7];
    const float* lin2_w = (const float*)d_in[8];
    const float* lin2_b = (const float*)d_in[9];
    const float* u2_w   = (const float*)d_in[10];
    const float* u2_cw  = (const float*)d_in[11];
    const float* u2_cb  = (const float*)d_in[12];
    const float* lino_w = (const float*)d_in[13];
    const float* lino_b = (const float*)d_in[14];

    float* out = (float*)d_out;
    unsigned short* wall = (unsigned short*)d_ws;         // 6*65536 bf16 = 768 KB
    float* pbuf = (float*)((char*)d_ws + 6 * 65536 * 2);  // 512 floats

    universal_p_kernel<<<dim3(2), dim3(256), 0, stream>>>(u1_w, u2_w, pbuf);
    prep_weights<<<dim3(192), dim3(256), 0, stream>>>(
        lin0_w, lin1_w, u1_cw, lin2_w, u2_cw, lino_w, wall);
    unet_fused<<<dim3(1024), dim3(256), 0, stream>>>(
        x, wall, lin0_b, lin1_b, u1_cb, lin2_b, u2_cb, lino_b, pbuf, out);
}